// Round 2
// baseline (544.729 us; speedup 1.0000x reference)
//
#include <hip/hip_runtime.h>
#include <math.h>

// ---------------- sizes ----------------
#define DD 256
#define KK 512
#define LL 64
#define BB 8
#define SS 16
#define F_LOG2PI 1.83787706641f
#define PER_I 16777216u   // stride of i dim in eps flat index (64*16*64*256)

// ---------------- threefry2x32 (JAX-compatible) ----------------
struct U2 { unsigned x, y; };

__host__ __device__ constexpr U2 tf2x32(unsigned k0, unsigned k1, unsigned c0, unsigned c1) {
  unsigned ks2 = k0 ^ k1 ^ 0x1BD11BDAu;
  unsigned x0 = c0 + k0;
  unsigned x1 = c1 + k1;
#define TFR(r) { x0 += x1; x1 = (x1 << (r)) | (x1 >> (32 - (r))); x1 ^= x0; }
  TFR(13) TFR(15) TFR(26) TFR(6)   x0 += k1;  x1 += ks2 + 1u;
  TFR(17) TFR(29) TFR(16) TFR(24)  x0 += ks2; x1 += k0 + 2u;
  TFR(13) TFR(15) TFR(26) TFR(6)   x0 += k0;  x1 += k1 + 3u;
  TFR(17) TFR(29) TFR(16) TFR(24)  x0 += k1;  x1 += ks2 + 4u;
  TFR(13) TFR(15) TFR(26) TFR(6)   x0 += ks2; x1 += k0 + 5u;
#undef TFR
  return U2{x0, x1};
}

// bits -> N(0,1) sample, matching jax.random.normal (uniform in [-1,1) + XLA erfinv)
__device__ inline float bits_to_normal(unsigned b) {
  float f = __uint_as_float((b >> 9) | 0x3f800000u) - 1.0f;   // [0,1)
  float u = fmaf(f, 2.0f, -0.99999994f);                      // f32(1-lo) == 2.0 exactly
  u = fmaxf(-0.99999994f, u);
  float w = -__logf(fmaf(-u, u, 1.0f));                       // -log(1-u*u)
  bool s = w < 5.0f;
  float ww = s ? (w - 2.5f) : (__builtin_amdgcn_sqrtf(w) - 3.0f);
  float p =          s ?  2.81022636e-08f : -0.000200214257f;
  p = fmaf(p, ww, s ?  3.43273939e-07f :  0.000100950558f);
  p = fmaf(p, ww, s ? -3.5233877e-06f  :  0.00134934322f);
  p = fmaf(p, ww, s ? -4.39150654e-06f : -0.00367342844f);
  p = fmaf(p, ww, s ?  0.00021858087f  :  0.00573950773f);
  p = fmaf(p, ww, s ? -0.00125372503f  : -0.0076224613f);
  p = fmaf(p, ww, s ? -0.00417768164f  :  0.00943887047f);
  p = fmaf(p, ww, s ?  0.246640727f    :  1.00167406f);
  p = fmaf(p, ww, s ?  1.50140941f     :  2.83297682f);
  return 1.41421356f * (p * u);                               // sqrt(2)*erfinv(u)
}

// ---------------- kernels ----------------

// Stable counting-sort of balanced labels. Robust to labels arriving as
// int64 (detected via per-class count != 8 under int32 interpretation).
__global__ void k_sort(const int* __restrict__ labels, int* __restrict__ pos,
                       int* __restrict__ lmap) {
  __shared__ int lab[512];
  __shared__ int cnt[64];
  __shared__ int mode;
  int t = threadIdx.x;
  int v = labels[t];
  if (t < 64) cnt[t] = 0;
  if (t == 0) mode = 0;
  __syncthreads();
  atomicAdd(&cnt[v & 63], 1);
  __syncthreads();
  if (t < 64 && cnt[t] != 8) mode = 1;   // benign same-value race
  __syncthreads();
  if (mode) v = labels[2 * t];           // int64 little-endian low words
  lab[t] = v & 63;
  __syncthreads();
  int c = lab[t];
  int o = 0;
  for (int j = 0; j < t; ++j) o += (lab[j] == c);
  pos[c * 8 + o] = t;                    // idx of o-th occurrence of class c
  if (t < 64) lmap[t] = t;               // balanced labels => identity class map
}

// Prototype fusion per (half, class l): fuse 4 support Gaussians.
__global__ void k_protos(const float* __restrict__ P, const float* __restrict__ he_p,
                         const int* __restrict__ pos, float* __restrict__ pm,
                         float* __restrict__ pe, float* __restrict__ pi,
                         float* __restrict__ cl) {
  int hb = blockIdx.x;             // h*64 + l
  int h = hb >> 6, l = hb & 63;
  int d = threadIdx.x;
  float eps_var = expf(he_p[0]);
  int soff = h ? 0 : 4;            // support rows for this half
  float sinv = 0.f, sminv = 0.f;
#pragma unroll
  for (int j = 0; j < 4; ++j) {
    int row = pos[l * 8 + soff + j];
    float m = P[row * KK + d];
    float hh = P[row * KK + DD + d];
    float vv = eps_var + expf(hh);
    float iv = 1.0f / vv;
    sinv += iv; sminv += m * iv;
  }
  float nv = 1.0f / sinv;          // fused variance
  float nm = nv * sminv;           // fused mean
  float ev = eps_var + nv;         // exp(h_proto)
  pm[hb * DD + d] = nm;
  pe[hb * DD + d] = ev;
  pi[hb * DD + d] = 1.0f / ev;     // exp(-h_proto)
  float t = F_LOG2PI + __logf(ev); // per-d constant of proto logpdf
  for (int off = 32; off; off >>= 1) t += __shfl_xor(t, off);
  __shared__ float red[4];
  int w = d >> 6, lane = d & 63;
  if (lane == 0) red[w] = t;
  __syncthreads();
  if (d == 0) cl[hb] = red[0] + red[1] + red[2] + red[3];
}

// lm[g,lq,lp] = logmls(query, proto)  (one block per (g,lq), thread=d)
__global__ void k_lm(const float* __restrict__ P, const int* __restrict__ pos,
                     const float* __restrict__ pm, const float* __restrict__ pe,
                     float* __restrict__ lm) {
  int bb = blockIdx.x;             // g*64 + lq
  int g = bb >> 6, lq = bb & 63;
  int h = g >> 2;
  int d = threadIdx.x;
  int row = pos[lq * 8 + g];
  float mq = P[row * KK + d];
  float vq = expf(P[row * KK + DD + d]);
  __shared__ float part[4][64];
  int w = d >> 6, lane = d & 63;
  for (int lp = 0; lp < 64; ++lp) {
    int pb = (h * 64 + lp) * DD + d;
    float mp = pm[pb], ev = pe[pb];
    float vs = vq + ev;
    float diff = mq - mp;
    float t = __logf(vs) + diff * diff * __builtin_amdgcn_rcpf(vs);
    for (int off = 32; off; off >>= 1) t += __shfl_xor(t, off);
    if (lane == 0) part[w][lp] = t;
  }
  __syncthreads();
  if (d < 64) {
    float s = part[0][d] + part[1][d] + part[2][d] + part[3][d];
    lm[bb * 64 + d] = -0.5f * (256.0f * F_LOG2PI + s);
  }
}

// Hot kernel: per (h,lq,s) block, loop lp; thread=d; 4 query rows i.
// Generates eps via threefry (partitionable scheme: counter=(0,e), bits = y0^y1),
// computes tl[i,lp] = logpdf(proto_lp, sample), then lse[i] = logsumexp_lp.
__global__ __launch_bounds__(256) void k_tl(const float* __restrict__ P,
    const int* __restrict__ pos, const float* __restrict__ pm,
    const float* __restrict__ pe, const float* __restrict__ pi,
    const float* __restrict__ cl, float* __restrict__ lse_ws) {
  constexpr U2 S1 = tf2x32(0u, 42u, 0u, 0u);  // foldlike split of key(42)
  constexpr U2 S2 = tf2x32(0u, 42u, 0u, 1u);
  int bb = blockIdx.x;             // h*1024 + lq*16 + s
  int h = bb >> 10;
  int lq = (bb >> 4) & 63;
  int s = bb & 15;
  int d = threadIdx.x;
  unsigned k0 = h ? S2.x : S1.x;
  unsigned k1 = h ? S2.y : S1.y;
  float mq[4], vq[4];
#pragma unroll
  for (int i = 0; i < 4; ++i) {
    int row = pos[lq * 8 + h * 4 + i];
    mq[i] = P[row * KK + d];
    vq[i] = expf(P[row * KK + DD + d]);
  }
  unsigned base0 = ((unsigned)lq * 16u + (unsigned)s) * 64u * 256u + (unsigned)d;
  __shared__ float part[4][4][64];  // [wave][i][lp]
  int w = d >> 6, lane = d & 63;
  for (int lp = 0; lp < 64; ++lp) {
    int pb = (h * 64 + lp) * DD + d;
    float mp = pm[pb], ev = pe[pb], ivp = pi[pb];
    unsigned e = base0 + (unsigned)lp * 256u;
    float t[4];
#pragma unroll
    for (int i = 0; i < 4; ++i) {
      U2 r = tf2x32(k0, k1, 0u, e + (unsigned)i * PER_I);
      float epsv = bits_to_normal(r.x ^ r.y);     // JAX partitionable 32-bit: y0 ^ y1
      float vs = vq[i] + ev;
      float ivs = __builtin_amdgcn_rcpf(vs);
      float m = (mq[i] * ev + mp * vq[i]) * ivs;  // product mean
      float vprod = vq[i] * ev * ivs;             // product variance
      float x = fmaf(__builtin_amdgcn_sqrtf(vprod), epsv, m);
      float diff = x - mp;
      t[i] = diff * diff * ivp;
    }
#pragma unroll
    for (int i = 0; i < 4; ++i)
      for (int off = 32; off; off >>= 1) t[i] += __shfl_xor(t[i], off);
    if (lane == 0) {
      part[w][0][lp] = t[0]; part[w][1][lp] = t[1];
      part[w][2][lp] = t[2]; part[w][3][lp] = t[3];
    }
  }
  __syncthreads();
  {
    int i = w;                     // wave w handles query i=w; lane = lp
    float sum = part[0][i][lane] + part[1][i][lane] + part[2][i][lane] + part[3][i][lane];
    float tlv = -0.5f * (cl[h * 64 + lane] + sum);
    float mx = tlv;
    for (int off = 32; off; off >>= 1) mx = fmaxf(mx, __shfl_xor(mx, off));
    float se = expf(tlv - mx);
    for (int off = 32; off; off >>= 1) se += __shfl_xor(se, off);
    if (lane == 0) {
      int g = h * 4 + i;
      lse_ws[(g * 64 + lq) * 16 + s] = mx + __logf(se);
    }
  }
}

// MC[g,lq] = logsumexp_s(-lse) - log S; out[pos[lq*8+g], lmap[lp]] = lm + MC
__global__ void k_final(const float* __restrict__ lm, const float* __restrict__ lse_ws,
                        const int* __restrict__ pos, const int* __restrict__ lmap,
                        float* __restrict__ out) {
  int bb = blockIdx.x;             // g*64 + lq
  int g = bb >> 6, lq = bb & 63;
  int t = threadIdx.x;             // 64 threads: lp
  float a = (t < 16) ? -lse_ws[bb * 16 + t] : -INFINITY;
  float mx = a;
  for (int off = 32; off; off >>= 1) mx = fmaxf(mx, __shfl_xor(mx, off));
  float e = (t < 16) ? expf(a - mx) : 0.0f;
  for (int off = 32; off; off >>= 1) e += __shfl_xor(e, off);
  float mc = mx + __logf(e) - 2.7725887f;   // - log(16)
  int row = pos[lq * 8 + g];
  out[row * 64 + lmap[t]] = lm[bb * 64 + t] + mc;
}

// ---------------- launch ----------------
extern "C" void kernel_launch(void* const* d_in, const int* in_sizes, int n_in,
                              void* d_out, int out_size, void* d_ws, size_t ws_size,
                              hipStream_t stream) {
  (void)in_sizes; (void)n_in; (void)out_size; (void)ws_size;
  const float* P      = (const float*)d_in[0];   // (512, 512) f32
  const float* he     = (const float*)d_in[1];   // scalar
  const int*   labels = (const int*)d_in[2];     // (512,) int
  float* out = (float*)d_out;                    // (512, 64) f32

  float* ws  = (float*)d_ws;
  float* pm  = ws;               // [2][64][256] proto mean
  float* pe  = ws + 32768;       // [2][64][256] exp(h_proto)
  float* pi  = ws + 65536;       // [2][64][256] exp(-h_proto)
  float* cl  = ws + 98304;       // [2][64] sum_d(LOG2PI + h_proto)
  float* lmw = ws + 98432;       // [8][64][64] lm
  float* lse = ws + 131200;      // [8][64][16] lse
  int*   pos = (int*)(ws + 139392);  // [512]
  int*   lmp = pos + 512;            // [64]

  hipLaunchKernelGGL(k_sort,   dim3(1),    dim3(512), 0, stream, labels, pos, lmp);
  hipLaunchKernelGGL(k_protos, dim3(128),  dim3(256), 0, stream, P, he, pos, pm, pe, pi, cl);
  hipLaunchKernelGGL(k_lm,     dim3(512),  dim3(256), 0, stream, P, pos, pm, pe, lmw);
  hipLaunchKernelGGL(k_tl,     dim3(2048), dim3(256), 0, stream, P, pos, pm, pe, pi, cl, lse);
  hipLaunchKernelGGL(k_final,  dim3(512),  dim3(64),  0, stream, lmw, lse, pos, lmp, out);
}

// Round 3
// 519.826 us; speedup vs baseline: 1.0479x; 1.0479x over previous
//
#include <hip/hip_runtime.h>
#include <math.h>

// ---------------- sizes ----------------
#define DD 256
#define KK 512
#define LL 64
#define BB 8
#define SS 16
#define F_LOG2PI 1.83787706641f
#define PER_I 16777216u   // i-stride in per-half eps flat index (64*16*64*256)

// ---------------- threefry2x32 (JAX-compatible) ----------------
struct U2 { unsigned x, y; };

__host__ __device__ constexpr U2 tf2x32(unsigned k0, unsigned k1, unsigned c0, unsigned c1) {
  unsigned ks2 = k0 ^ k1 ^ 0x1BD11BDAu;
  unsigned x0 = c0 + k0;
  unsigned x1 = c1 + k1;
#define TFR(r) { x0 += x1; x1 = (x1 << (r)) | (x1 >> (32 - (r))); x1 ^= x0; }
  TFR(13) TFR(15) TFR(26) TFR(6)   x0 += k1;  x1 += ks2 + 1u;
  TFR(17) TFR(29) TFR(16) TFR(24)  x0 += ks2; x1 += k0 + 2u;
  TFR(13) TFR(15) TFR(26) TFR(6)   x0 += k0;  x1 += k1 + 3u;
  TFR(17) TFR(29) TFR(16) TFR(24)  x0 += k1;  x1 += ks2 + 4u;
  TFR(13) TFR(15) TFR(26) TFR(6)   x0 += ks2; x1 += k0 + 5u;
#undef TFR
  return U2{x0, x1};
}

// bits -> N(0,1), matching jax.random.normal (u in [-1,1) + XLA Giles erfinv)
__device__ inline float bits_to_normal(unsigned b) {
  float f = __uint_as_float((b >> 9) | 0x3f800000u) - 1.0f;   // [0,1)
  float u = fmaf(f, 2.0f, -0.99999994f);                      // >= lo always (f>=0)
  float w = -__logf(fmaf(-u, u, 1.0f));                       // -log(1-u*u)
  bool s = w < 5.0f;
  float ww = s ? (w - 2.5f) : (__builtin_amdgcn_sqrtf(w) - 3.0f);
  float p =          s ?  2.81022636e-08f : -0.000200214257f;
  p = fmaf(p, ww, s ?  3.43273939e-07f :  0.000100950558f);
  p = fmaf(p, ww, s ? -3.5233877e-06f  :  0.00134934322f);
  p = fmaf(p, ww, s ? -4.39150654e-06f : -0.00367342844f);
  p = fmaf(p, ww, s ?  0.00021858087f  :  0.00573950773f);
  p = fmaf(p, ww, s ? -0.00125372503f  : -0.0076224613f);
  p = fmaf(p, ww, s ? -0.00417768164f  :  0.00943887047f);
  p = fmaf(p, ww, s ?  0.246640727f    :  1.00167406f);
  p = fmaf(p, ww, s ?  1.50140941f     :  2.83297682f);
  return 1.41421356f * (p * u);                               // sqrt(2)*erfinv(u)
}

// ---------------- kernels ----------------

// Stable counting-sort of balanced labels (robust to int64 labels).
__global__ void k_sort(const int* __restrict__ labels, int* __restrict__ pos,
                       int* __restrict__ lmap) {
  __shared__ int lab[512];
  __shared__ int cnt[64];
  __shared__ int mode;
  int t = threadIdx.x;
  int v = labels[t];
  if (t < 64) cnt[t] = 0;
  if (t == 0) mode = 0;
  __syncthreads();
  atomicAdd(&cnt[v & 63], 1);
  __syncthreads();
  if (t < 64 && cnt[t] != 8) mode = 1;
  __syncthreads();
  if (mode) v = labels[2 * t];           // int64 little-endian low words
  lab[t] = v & 63;
  __syncthreads();
  int c = lab[t];
  int o = 0;
  for (int j = 0; j < t; ++j) o += (lab[j] == c);
  pos[c * 8 + o] = t;
  if (t < 64) lmap[t] = t;
}

// Prototype fusion per (half, class l). Emits:
//   pm/pe        [h][l][d]  (for k_lm, d-coalesced)
//   protoQ float4[h][d][l] = {mp, ev, 1/ev, 0}  (for k_tl, lp-coalesced)
//   cl           [h][l] = sum_d(LOG2PI + log ev)
__global__ void k_protos(const float* __restrict__ P, const float* __restrict__ he_p,
                         const int* __restrict__ pos, float* __restrict__ pm,
                         float* __restrict__ pe, float4* __restrict__ pq,
                         float* __restrict__ cl) {
  int hb = blockIdx.x;             // h*64 + l
  int h = hb >> 6, l = hb & 63;
  int d = threadIdx.x;
  float eps_var = expf(he_p[0]);
  int soff = h ? 0 : 4;            // support rows for this half
  float sinv = 0.f, sminv = 0.f;
#pragma unroll
  for (int j = 0; j < 4; ++j) {
    int row = pos[l * 8 + soff + j];
    float m = P[row * KK + d];
    float hh = P[row * KK + DD + d];
    float vv = eps_var + expf(hh);
    float iv = 1.0f / vv;
    sinv += iv; sminv += m * iv;
  }
  float nv = 1.0f / sinv;
  float nm = nv * sminv;
  float ev = eps_var + nv;         // exp(h_proto)
  pm[hb * DD + d] = nm;
  pe[hb * DD + d] = ev;
  float4 rec; rec.x = nm; rec.y = ev; rec.z = 1.0f / ev; rec.w = 0.0f;
  pq[(h * 256 + d) * 64 + l] = rec;
  float t = F_LOG2PI + __logf(ev);
  for (int off = 32; off; off >>= 1) t += __shfl_xor(t, off);
  __shared__ float red[4];
  int w = d >> 6, lane = d & 63;
  if (lane == 0) red[w] = t;
  __syncthreads();
  if (d == 0) cl[hb] = red[0] + red[1] + red[2] + red[3];
}

// lm[g,lq,lp] = logmls(query, proto)
__global__ void k_lm(const float* __restrict__ P, const int* __restrict__ pos,
                     const float* __restrict__ pm, const float* __restrict__ pe,
                     float* __restrict__ lm) {
  int bb = blockIdx.x;             // g*64 + lq
  int g = bb >> 6, lq = bb & 63;
  int h = g >> 2;
  int d = threadIdx.x;
  int row = pos[lq * 8 + g];
  float mq = P[row * KK + d];
  float vq = expf(P[row * KK + DD + d]);
  __shared__ float part[4][64];
  int w = d >> 6, lane = d & 63;
  for (int lp = 0; lp < 64; ++lp) {
    int pb = (h * 64 + lp) * DD + d;
    float mp = pm[pb], ev = pe[pb];
    float vs = vq + ev;
    float diff = mq - mp;
    float t = __logf(vs) + diff * diff * __builtin_amdgcn_rcpf(vs);
    for (int off = 32; off; off >>= 1) t += __shfl_xor(t, off);
    if (lane == 0) part[w][lp] = t;
  }
  __syncthreads();
  if (d < 64) {
    float s = part[0][d] + part[1][d] + part[2][d] + part[3][d];
    lm[bb * 64 + d] = -0.5f * (256.0f * F_LOG2PI + s);
  }
}

// Hot kernel, restructured: block=(h,lq,s); wave w = query i; lane = lp.
// Serial accumulation over d (no per-iteration shuffles/LDS/barriers).
// Proto via coalesced float4 loads from protoQ[h][d][lp]; query via LDS
// broadcast (same addr across lanes = free). RNG: threefry(0, e), bits=y0^y1.
__global__ __launch_bounds__(256) void k_tl(const float* __restrict__ P,
    const int* __restrict__ pos, const float4* __restrict__ pq,
    const float* __restrict__ cl, float* __restrict__ lse_ws) {
  constexpr U2 S1 = tf2x32(0u, 42u, 0u, 0u);  // foldlike split of key(42)
  constexpr U2 S2 = tf2x32(0u, 42u, 0u, 1u);
  int bb = blockIdx.x;             // h*1024 + lq*16 + s
  int h = bb >> 10;
  int lq = (bb >> 4) & 63;
  int s = bb & 15;
  int t = threadIdx.x;

  __shared__ float2 q[4 * 256];    // [i][d] = {m, exp(h)}
#pragma unroll
  for (int i = 0; i < 4; ++i) {
    int row = pos[lq * 8 + h * 4 + i];
    float2 rec;
    rec.x = P[row * KK + t];
    rec.y = expf(P[row * KK + DD + t]);
    q[i * 256 + t] = rec;
  }
  __syncthreads();

  int w = t >> 6, lane = t & 63;   // w = query i, lane = lp
  unsigned k0 = h ? S2.x : S1.x;
  unsigned k1 = h ? S2.y : S1.y;
  unsigned ebase = (unsigned)w * PER_I +
                   (((unsigned)lq * 16u + (unsigned)s) * 64u + (unsigned)lane) * 256u;
  const float2* qd = &q[w * 256];
  const float4* pp = pq + (h * 256) * 64 + lane;
  float acc = 0.0f;
#pragma unroll 4
  for (int d = 0; d < 256; ++d) {
    float4 pr = pp[d * 64];            // {mp, ev, ivp, -} coalesced, L2-hot
    float2 qv = qd[d];                 // broadcast ds_read_b64
    float vs  = qv.y + pr.y;
    float ivs = __builtin_amdgcn_rcpf(vs);
    float evs = pr.y * ivs;            // ev/vs
    float a   = (qv.x - pr.x) * evs;   // product-mean minus mp
    float sig = __builtin_amdgcn_sqrtf(qv.y * evs);
    U2 r = tf2x32(k0, k1, 0u, ebase + (unsigned)d);
    float eps = bits_to_normal(r.x ^ r.y);
    float diff = fmaf(sig, eps, a);
    acc = fmaf(diff * diff, pr.z, acc);
  }
  // per-wave logsumexp over lane = lp
  float tlv = -0.5f * (cl[h * 64 + lane] + acc);
  float mx = tlv;
  for (int off = 32; off; off >>= 1) mx = fmaxf(mx, __shfl_xor(mx, off));
  float se = expf(tlv - mx);
  for (int off = 32; off; off >>= 1) se += __shfl_xor(se, off);
  if (lane == 0) {
    int g = h * 4 + w;
    lse_ws[(g * 64 + lq) * 16 + s] = mx + __logf(se);
  }
}

// MC[g,lq] = logsumexp_s(-lse) - log S; out[pos[lq*8+g], lmap[lp]] = lm + MC
__global__ void k_final(const float* __restrict__ lm, const float* __restrict__ lse_ws,
                        const int* __restrict__ pos, const int* __restrict__ lmap,
                        float* __restrict__ out) {
  int bb = blockIdx.x;             // g*64 + lq
  int g = bb >> 6, lq = bb & 63;
  int t = threadIdx.x;             // 64 threads: lp
  float a = (t < 16) ? -lse_ws[bb * 16 + t] : -INFINITY;
  float mx = a;
  for (int off = 32; off; off >>= 1) mx = fmaxf(mx, __shfl_xor(mx, off));
  float e = (t < 16) ? expf(a - mx) : 0.0f;
  for (int off = 32; off; off >>= 1) e += __shfl_xor(e, off);
  float mc = mx + __logf(e) - 2.7725887f;   // - log(16)
  int row = pos[lq * 8 + g];
  out[row * 64 + lmap[t]] = lm[bb * 64 + t] + mc;
}

// ---------------- launch ----------------
extern "C" void kernel_launch(void* const* d_in, const int* in_sizes, int n_in,
                              void* d_out, int out_size, void* d_ws, size_t ws_size,
                              hipStream_t stream) {
  (void)in_sizes; (void)n_in; (void)out_size; (void)ws_size;
  const float* P      = (const float*)d_in[0];   // (512, 512) f32
  const float* he     = (const float*)d_in[1];   // scalar
  const int*   labels = (const int*)d_in[2];     // (512,) int
  float* out = (float*)d_out;                    // (512, 64) f32

  float* ws = (float*)d_ws;
  float4* pq = (float4*)ws;            // [2][256][64] float4 = 131072 floats
  float* pm  = ws + 131072;            // [2][64][256]
  float* pe  = ws + 163840;            // [2][64][256]
  float* cl  = ws + 196608;            // [2][64]
  float* lmw = ws + 196736;            // [8][64][64]
  float* lse = ws + 229504;            // [8][64][16]
  int*   pos = (int*)(ws + 237696);    // [512]
  int*   lmp = pos + 512;              // [64]

  hipLaunchKernelGGL(k_sort,   dim3(1),    dim3(512), 0, stream, labels, pos, lmp);
  hipLaunchKernelGGL(k_protos, dim3(128),  dim3(256), 0, stream, P, he, pos, pm, pe, pq, cl);
  hipLaunchKernelGGL(k_lm,     dim3(512),  dim3(256), 0, stream, P, pos, pm, pe, lmw);
  hipLaunchKernelGGL(k_tl,     dim3(2048), dim3(256), 0, stream, P, pos, pq, cl, lse);
  hipLaunchKernelGGL(k_final,  dim3(512),  dim3(64),  0, stream, lmw, lse, pos, lmp, out);
}

// Round 4
// 456.404 us; speedup vs baseline: 1.1935x; 1.1390x over previous
//
#include <hip/hip_runtime.h>
#include <math.h>

// ---------------- sizes ----------------
#define DD 256
#define KK 512
#define LL 64
#define BB 8
#define SS 16
#define F_LOG2PI 1.83787706641f
#define PER_I 16777216u   // i-stride in per-half eps flat index (64*16*64*256)

// ---------------- threefry2x32 (JAX-compatible) ----------------
struct U2 { unsigned x, y; };

__host__ __device__ constexpr U2 tf2x32(unsigned k0, unsigned k1, unsigned c0, unsigned c1) {
  unsigned ks2 = k0 ^ k1 ^ 0x1BD11BDAu;
  unsigned x0 = c0 + k0;
  unsigned x1 = c1 + k1;
#define TFR(r) { x0 += x1; x1 = (x1 << (r)) | (x1 >> (32 - (r))); x1 ^= x0; }
  TFR(13) TFR(15) TFR(26) TFR(6)   x0 += k1;  x1 += ks2 + 1u;
  TFR(17) TFR(29) TFR(16) TFR(24)  x0 += ks2; x1 += k0 + 2u;
  TFR(13) TFR(15) TFR(26) TFR(6)   x0 += k0;  x1 += k1 + 3u;
  TFR(17) TFR(29) TFR(16) TFR(24)  x0 += k1;  x1 += ks2 + 4u;
  TFR(13) TFR(15) TFR(26) TFR(6)   x0 += ks2; x1 += k0 + 5u;
#undef TFR
  return U2{x0, x1};
}

// bits -> N(0,1), matching jax.random.normal (u in [-1,1) + XLA Giles erfinv)
// DO NOT TOUCH: verified bit-compatible (absmax 0.125 passing).
__device__ inline float bits_to_normal(unsigned b) {
  float f = __uint_as_float((b >> 9) | 0x3f800000u) - 1.0f;   // [0,1)
  float u = fmaf(f, 2.0f, -0.99999994f);                      // >= lo always (f>=0)
  float w = -__logf(fmaf(-u, u, 1.0f));                       // -log(1-u*u)
  bool s = w < 5.0f;
  float ww = s ? (w - 2.5f) : (__builtin_amdgcn_sqrtf(w) - 3.0f);
  float p =          s ?  2.81022636e-08f : -0.000200214257f;
  p = fmaf(p, ww, s ?  3.43273939e-07f :  0.000100950558f);
  p = fmaf(p, ww, s ? -3.5233877e-06f  :  0.00134934322f);
  p = fmaf(p, ww, s ? -4.39150654e-06f : -0.00367342844f);
  p = fmaf(p, ww, s ?  0.00021858087f  :  0.00573950773f);
  p = fmaf(p, ww, s ? -0.00125372503f  : -0.0076224613f);
  p = fmaf(p, ww, s ? -0.00417768164f  :  0.00943887047f);
  p = fmaf(p, ww, s ?  0.246640727f    :  1.00167406f);
  p = fmaf(p, ww, s ?  1.50140941f     :  2.83297682f);
  return 1.41421356f * (p * u);                               // sqrt(2)*erfinv(u)
}

// ---------------- kernels ----------------

// Stable counting-sort of balanced labels (robust to int64 labels).
__global__ void k_sort(const int* __restrict__ labels, int* __restrict__ pos,
                       int* __restrict__ lmap) {
  __shared__ int lab[512];
  __shared__ int cnt[64];
  __shared__ int mode;
  int t = threadIdx.x;
  int v = labels[t];
  if (t < 64) cnt[t] = 0;
  if (t == 0) mode = 0;
  __syncthreads();
  atomicAdd(&cnt[v & 63], 1);
  __syncthreads();
  if (t < 64 && cnt[t] != 8) mode = 1;
  __syncthreads();
  if (mode) v = labels[2 * t];           // int64 little-endian low words
  lab[t] = v & 63;
  __syncthreads();
  int c = lab[t];
  int o = 0;
  for (int j = 0; j < t; ++j) o += (lab[j] == c);
  pos[c * 8 + o] = t;
  if (t < 64) lmap[t] = t;
}

// Prototype fusion per (half, class l). Emits pm/pe ([h][l][d], for k_lm),
// protoQ float4[h][d][l] = {mp, ev, 1/ev, 0} (lp-coalesced, for k_tl),
// cl[h][l] = sum_d(LOG2PI + log ev).
__global__ void k_protos(const float* __restrict__ P, const float* __restrict__ he_p,
                         const int* __restrict__ pos, float* __restrict__ pm,
                         float* __restrict__ pe, float4* __restrict__ pq,
                         float* __restrict__ cl) {
  int hb = blockIdx.x;             // h*64 + l
  int h = hb >> 6, l = hb & 63;
  int d = threadIdx.x;
  float eps_var = expf(he_p[0]);
  int soff = h ? 0 : 4;            // support rows for this half
  float sinv = 0.f, sminv = 0.f;
#pragma unroll
  for (int j = 0; j < 4; ++j) {
    int row = pos[l * 8 + soff + j];
    float m = P[row * KK + d];
    float hh = P[row * KK + DD + d];
    float vv = eps_var + expf(hh);
    float iv = 1.0f / vv;
    sinv += iv; sminv += m * iv;
  }
  float nv = 1.0f / sinv;
  float nm = nv * sminv;
  float ev = eps_var + nv;         // exp(h_proto)
  pm[hb * DD + d] = nm;
  pe[hb * DD + d] = ev;
  float4 rec; rec.x = nm; rec.y = ev; rec.z = 1.0f / ev; rec.w = 0.0f;
  pq[(h * 256 + d) * 64 + l] = rec;
  float t = F_LOG2PI + __logf(ev);
  for (int off = 32; off; off >>= 1) t += __shfl_xor(t, off);
  __shared__ float red[4];
  int w = d >> 6, lane = d & 63;
  if (lane == 0) red[w] = t;
  __syncthreads();
  if (d == 0) cl[hb] = red[0] + red[1] + red[2] + red[3];
}

// lm[g,lq,lp] = logmls(query, proto)
__global__ void k_lm(const float* __restrict__ P, const int* __restrict__ pos,
                     const float* __restrict__ pm, const float* __restrict__ pe,
                     float* __restrict__ lm) {
  int bb = blockIdx.x;             // g*64 + lq
  int g = bb >> 6, lq = bb & 63;
  int h = g >> 2;
  int d = threadIdx.x;
  int row = pos[lq * 8 + g];
  float mq = P[row * KK + d];
  float vq = expf(P[row * KK + DD + d]);
  __shared__ float part[4][64];
  int w = d >> 6, lane = d & 63;
  for (int lp = 0; lp < 64; ++lp) {
    int pb = (h * 64 + lp) * DD + d;
    float mp = pm[pb], ev = pe[pb];
    float vs = vq + ev;
    float diff = mq - mp;
    float t = __logf(vs) + diff * diff * __builtin_amdgcn_rcpf(vs);
    for (int off = 32; off; off >>= 1) t += __shfl_xor(t, off);
    if (lane == 0) part[w][lp] = t;
  }
  __syncthreads();
  if (d < 64) {
    float s = part[0][d] + part[1][d] + part[2][d] + part[3][d];
    lm[bb * 64 + d] = -0.5f * (256.0f * F_LOG2PI + s);
  }
}

// Hot kernel: block=(h, lq, dchunk of 16). wave w = query i, lane = lp.
// d outer (prep amortized), s=0..15 inner fully unrolled -> 16 independent
// threefry chains per lane (hides VALU dep latency). Partial d-sums are
// atomically accumulated into accbuf[(g*64+lq)*16+s)*64+lp].
__global__ __launch_bounds__(256) void k_tl(const float* __restrict__ P,
    const int* __restrict__ pos, const float4* __restrict__ pq,
    float* __restrict__ accbuf) {
  constexpr U2 S1 = tf2x32(0u, 42u, 0u, 0u);  // foldlike split of key(42)
  constexpr U2 S2 = tf2x32(0u, 42u, 0u, 1u);
  int bb = blockIdx.x;             // h*1024 + lq*16 + chunk
  int h = bb >> 10;
  int lq = (bb >> 4) & 63;
  int chunk = bb & 15;
  int t = threadIdx.x;

  __shared__ float2 q[4 * 256];    // [i][d] = {m, exp(h)}
#pragma unroll
  for (int i = 0; i < 4; ++i) {
    int row = pos[lq * 8 + h * 4 + i];
    float2 rec;
    rec.x = P[row * KK + t];
    rec.y = expf(P[row * KK + DD + t]);
    q[i * 256 + t] = rec;
  }
  __syncthreads();

  int w = t >> 6, lane = t & 63;   // w = query i, lane = lp
  unsigned k0 = h ? S2.x : S1.x;
  unsigned k1 = h ? S2.y : S1.y;
  // eps flat idx (per half) = i*PER_I + lq*262144 + s*16384 + lp*256 + d
  unsigned ebase = (unsigned)w * PER_I + (unsigned)lq * 262144u +
                   (unsigned)lane * 256u + (unsigned)chunk * 16u;
  const float2* qd = &q[w * 256];
  const float4* pp = pq + (h * 256 + chunk * 16) * 64 + lane;

  float acc[16];
#pragma unroll
  for (int s = 0; s < 16; ++s) acc[s] = 0.0f;

#pragma unroll 1
  for (int dd = 0; dd < 16; ++dd) {
    float4 pr = pp[dd * 64];           // {mp, ev, ivp, -} coalesced, L2-hot
    float2 qv = qd[chunk * 16 + dd];   // broadcast ds_read_b64
    float vs  = qv.y + pr.y;
    float ivs = __builtin_amdgcn_rcpf(vs);
    float evs = pr.y * ivs;            // ev/vs
    float sivp = __builtin_amdgcn_sqrtf(pr.z);
    float A = (qv.x - pr.x) * evs * sivp;                    // (pm-mean)*sqrt(ivp), negated sign irrelevant (squared)
    float S = __builtin_amdgcn_sqrtf(qv.y * evs) * sivp;     // sigma*sqrt(ivp)
    unsigned ed = ebase + (unsigned)dd;
#pragma unroll
    for (int s = 0; s < 16; ++s) {
      U2 r = tf2x32(k0, k1, 0u, ed + (unsigned)s * 16384u);
      float eps = bits_to_normal(r.x ^ r.y);
      float diff = fmaf(S, eps, A);
      acc[s] = fmaf(diff, diff, acc[s]);
    }
  }

  int g = h * 4 + w;
  float* dst = accbuf + ((g * 64 + lq) * 16) * 64 + lane;
#pragma unroll
  for (int s = 0; s < 16; ++s) atomicAdd(dst + s * 64, acc[s]);
}

// Per (g,lq,s): tl = -0.5*(cl + sum_d); lse over lane=lp -> lse_ws
__global__ void k_lse(const float* __restrict__ accbuf, const float* __restrict__ cl,
                      float* __restrict__ lse_ws) {
  int idx = blockIdx.x * 4 + (threadIdx.x >> 6);  // (g*64+lq)*16+s
  int lane = threadIdx.x & 63;                    // lp
  int g = idx >> 10;
  int h = g >> 2;
  float tlv = -0.5f * (cl[h * 64 + lane] + accbuf[idx * 64 + lane]);
  float mx = tlv;
  for (int off = 32; off; off >>= 1) mx = fmaxf(mx, __shfl_xor(mx, off));
  float se = expf(tlv - mx);
  for (int off = 32; off; off >>= 1) se += __shfl_xor(se, off);
  if (lane == 0) lse_ws[idx] = mx + __logf(se);
}

// MC[g,lq] = logsumexp_s(-lse) - log S; out[pos[lq*8+g], lmap[lp]] = lm + MC
__global__ void k_final(const float* __restrict__ lm, const float* __restrict__ lse_ws,
                        const int* __restrict__ pos, const int* __restrict__ lmap,
                        float* __restrict__ out) {
  int bb = blockIdx.x;             // g*64 + lq
  int g = bb >> 6, lq = bb & 63;
  int t = threadIdx.x;             // 64 threads: lp
  float a = (t < 16) ? -lse_ws[bb * 16 + t] : -INFINITY;
  float mx = a;
  for (int off = 32; off; off >>= 1) mx = fmaxf(mx, __shfl_xor(mx, off));
  float e = (t < 16) ? expf(a - mx) : 0.0f;
  for (int off = 32; off; off >>= 1) e += __shfl_xor(e, off);
  float mc = mx + __logf(e) - 2.7725887f;   // - log(16)
  int row = pos[lq * 8 + g];
  out[row * 64 + lmap[t]] = lm[bb * 64 + t] + mc;
}

// ---------------- launch ----------------
extern "C" void kernel_launch(void* const* d_in, const int* in_sizes, int n_in,
                              void* d_out, int out_size, void* d_ws, size_t ws_size,
                              hipStream_t stream) {
  (void)in_sizes; (void)n_in; (void)out_size; (void)ws_size;
  const float* P      = (const float*)d_in[0];   // (512, 512) f32
  const float* he     = (const float*)d_in[1];   // scalar
  const int*   labels = (const int*)d_in[2];     // (512,) int
  float* out = (float*)d_out;                    // (512, 64) f32

  float* ws = (float*)d_ws;
  float* accbuf = ws;                   // [8][64][16][64] = 524288 floats (2 MB)
  float4* pq = (float4*)(ws + 524288);  // [2][256][64] float4 = 131072 floats
  float* pm  = ws + 655360;             // [2][64][256]
  float* pe  = ws + 688128;             // [2][64][256]
  float* cl  = ws + 720896;             // [2][64]
  float* lmw = ws + 721024;             // [8][64][64]
  float* lse = ws + 753792;             // [8][64][16]
  int*   pos = (int*)(ws + 761984);     // [512]
  int*   lmp = pos + 512;               // [64]

  hipMemsetAsync(accbuf, 0, 524288 * sizeof(float), stream);
  hipLaunchKernelGGL(k_sort,   dim3(1),    dim3(512), 0, stream, labels, pos, lmp);
  hipLaunchKernelGGL(k_protos, dim3(128),  dim3(256), 0, stream, P, he, pos, pm, pe, pq, cl);
  hipLaunchKernelGGL(k_lm,     dim3(512),  dim3(256), 0, stream, P, pos, pm, pe, lmw);
  hipLaunchKernelGGL(k_tl,     dim3(2048), dim3(256), 0, stream, P, pos, pq, accbuf);
  hipLaunchKernelGGL(k_lse,    dim3(2048), dim3(256), 0, stream, accbuf, cl, lse);
  hipLaunchKernelGGL(k_final,  dim3(512),  dim3(64),  0, stream, lmw, lse, pos, lmp, out);
}